// Round 17
// baseline (902.657 us; speedup 1.0000x reference)
//
#include <hip/hip_runtime.h>
#include <math.h>

#define H 4
#define D 32
#define C 128
#define CC (C * C)
#define SC 2048
#define LST 136   // LDS row stride (shorts); 272B = multiple of 16 -> aligned b128 reads
#define SHST 68
#define RSC 0.17677669529663687f

typedef unsigned short ushort_t;
typedef __attribute__((ext_vector_type(8))) short bf16x8;
typedef __attribute__((ext_vector_type(4))) float f32x4;

union BF8 { bf16x8 v; ushort_t u[8]; };

// ---------- helpers ----------
__device__ __forceinline__ float bf2f(ushort_t u) {
    return __uint_as_float(((unsigned)u) << 16);
}
__device__ __forceinline__ ushort_t f2bf(float f) {
    unsigned u = __float_as_uint(f);
    u += 0x7fffu + ((u >> 16) & 1u);
    return (ushort_t)(u >> 16);
}
__device__ __forceinline__ void unpack2(unsigned w, float& a, float& b) {
    a = __uint_as_float(w << 16);
    b = __uint_as_float(w & 0xffff0000u);
}
__device__ __forceinline__ unsigned pack2(float a, float b) {
    return ((unsigned)f2bf(b) << 16) | (unsigned)f2bf(a);
}
__device__ __forceinline__ unsigned blend2(unsigned yw, unsigned ow, float g) {
    float y0, y1, o0, o1;
    unpack2(yw, y0, y1); unpack2(ow, o0, o1);
    return pack2(g * y0 + (1.f - g) * o0, g * y1 + (1.f - g) * o1);
}
__device__ __forceinline__ float gelu_t(float x) {
    float z = 0.7978845608028654f * (x + 0.044715f * x * x * x);
    float t = 1.0f - 2.0f / (__expf(2.0f * z) + 1.0f);
    return 0.5f * x * (1.0f + t);
}

// ---------- diag ----------
__global__ void diag_fill(float* out, int n, float v) {
    int i = blockIdx.x * 256 + threadIdx.x;
    if (i < n) out[i] = v;
}

// ---------- fused relation weights (fp32): W' = W @ blockdiag(rel) ----------
__global__ void fuse_weights(const float* __restrict__ kW, const float* __restrict__ kb,
                             const float* __restrict__ vW, const float* __restrict__ vb,
                             const float* __restrict__ relA, const float* __restrict__ relM,
                             float* __restrict__ fw)
{
    int bid = blockIdx.x;      // 0..11
    int le = bid >> 1;         // l*3+e
    int which = bid & 1;       // 0 = k/relA, 1 = v/relM
    int l = le / 3, e = le % 3;
    const int est[3] = {1, 0, 0};
    int st = est[e];
    const float* Wsrc = (which ? vW : kW) + (size_t)(l * 2 + st) * CC;
    const float* bsrc = (which ? vb : kb) + (size_t)(l * 2 + st) * C;
    const float* rel  = (which ? relM : relA) + (size_t)(l * 3 + e) * H * D * D;
    float* out = fw + (size_t)(le * 2 + which) * (CC + C);

    __shared__ float rsh[H * D * D];
    for (int i = threadIdx.x; i < H * D * D; i += 256) rsh[i] = rel[i];
    __syncthreads();

    for (int i = threadIdx.x; i < CC; i += 256) {
        int c = i >> 7, hf = i & 127, h = hf >> 5, f = hf & 31;
        float acc = 0.f;
        #pragma unroll
        for (int d = 0; d < D; ++d)
            acc += Wsrc[c * C + h * D + d] * rsh[h * D * D + d * D + f];
        out[i] = acc;
    }
    for (int i = threadIdx.x; i < C; i += 256) {
        int h = i >> 5, f = i & 31;
        float acc = 0.f;
        #pragma unroll
        for (int d = 0; d < D; ++d)
            acc += bsrc[h * D + d] * rsh[h * D * D + d * D + f];
        out[CC + i] = acc;
    }
}

// ---------- transpose all weights to bf16 Wt[n][k] ----------
__global__ void trans_w(const float* __restrict__ lin0_W, const float* __restrict__ qW,
                        const float* __restrict__ aW, const float* __restrict__ fw,
                        ushort_t* __restrict__ wt)
{
    int id = blockIdx.x;
    const float* src;
    if (id < 2)       src = lin0_W + (size_t)id * CC;
    else if (id < 6)  src = qW + (size_t)(id - 2) * CC;
    else if (id < 10) src = aW + (size_t)(id - 6) * CC;
    else              src = fw + (size_t)(id - 10) * (CC + C);
    ushort_t* dst = wt + (size_t)id * CC;
    for (int i = threadIdx.x; i < CC; i += 256) {
        int n = i >> 7, k = i & 127;
        dst[i] = f2bf(src[k * C + n]);
    }
}

// ---------- fused two-stage MFMA kernel ----------
struct WJob { const ushort_t* w; const float* b; ushort_t* y; int ystride; };
struct FusedArgs {
    const void* X; const ushort_t* W1; const float* b1; ushort_t* Y1;  // Y1 may be null (skip store)
    const ushort_t* Old; const float* skipp; int N; int nw;
    WJob j[3];
};

// GEMM1: Y1 = post(X @ W1^T + b1); chain: for w<nw, Y_w = Y1 @ Wt_w^T + b_w (from LDS).
// Chained outputs staged per-wave (no barriers in the chain loop).
template <int INTYPE, int PRE, int POST>
__global__ __launch_bounds__(256, 4) void fusedProj(FusedArgs A0, FusedArgs A1, int tiles0)
{
    __shared__ ushort_t lds[64 * LST];        // 17408 B: GEMM1 tile / a2 source
    __shared__ ushort_t sh2[4][32 * SHST];    // 17408 B: per-wave chained staging
    const bool sel0 = ((int)blockIdx.x < tiles0);
    const FusedArgs& A = sel0 ? A0 : A1;
    const int t = sel0 ? (int)blockIdx.x : (int)blockIdx.x - tiles0;
    const int N = A.N;
    const int wave = threadIdx.x >> 6, lane = threadIdx.x & 63;
    const int wr = wave >> 1, wc = wave & 1;
    const int lr = lane & 15, lk = lane >> 4;
    const int rr2 = lane >> 4, c4 = lane & 15;
    const int row0 = t << 6;
    const int rbase = row0 + wr * 32;

    BF8 a[2][4];
    #pragma unroll
    for (int m = 0; m < 2; ++m) {
        const int r = rbase + m * 16 + lr;
        #pragma unroll
        for (int kk = 0; kk < 4; ++kk) {
            if (INTYPE == 0) {
                float vv[8];
                if (r < N) {
                    const float* p = (const float*)A.X + (size_t)r * C + kk * 32 + lk * 8;
                    float4 u0 = *(const float4*)p;
                    float4 u1 = *(const float4*)(p + 4);
                    vv[0] = u0.x; vv[1] = u0.y; vv[2] = u0.z; vv[3] = u0.w;
                    vv[4] = u1.x; vv[5] = u1.y; vv[6] = u1.z; vv[7] = u1.w;
                } else {
                    #pragma unroll
                    for (int q = 0; q < 8; ++q) vv[q] = 0.f;
                }
                #pragma unroll
                for (int q = 0; q < 8; ++q) a[m][kk].u[q] = f2bf(PRE ? gelu_t(vv[q]) : vv[q]);
            } else {
                if (r < N) {
                    a[m][kk].v = *(const bf16x8*)((const ushort_t*)A.X + (size_t)r * C + kk * 32 + lk * 8);
                    if (PRE) {
                        #pragma unroll
                        for (int q = 0; q < 8; ++q) a[m][kk].u[q] = f2bf(gelu_t(bf2f(a[m][kk].u[q])));
                    }
                } else {
                    #pragma unroll
                    for (int q = 0; q < 8; ++q) a[m][kk].u[q] = 0;
                }
            }
        }
    }

    // ---- GEMM1 ----
    {
        f32x4 acc[2][4];
        #pragma unroll
        for (int m = 0; m < 2; ++m)
            #pragma unroll
            for (int n = 0; n < 4; ++n)
                acc[m][n] = (f32x4){0.f, 0.f, 0.f, 0.f};

        #pragma unroll
        for (int kk = 0; kk < 4; ++kk) {
            #pragma unroll
            for (int n = 0; n < 4; ++n) {
                BF8 b;
                b.v = *(const bf16x8*)(A.W1 + (size_t)(wc * 64 + n * 16 + lr) * C + kk * 32 + lk * 8);
                acc[0][n] = __builtin_amdgcn_mfma_f32_16x16x32_bf16(a[0][kk].v, b.v, acc[0][n], 0, 0, 0);
                acc[1][n] = __builtin_amdgcn_mfma_f32_16x16x32_bf16(a[1][kk].v, b.v, acc[1][n], 0, 0, 0);
            }
        }

        float bc[4];
        #pragma unroll
        for (int n = 0; n < 4; ++n) bc[n] = A.b1[wc * 64 + n * 16 + lr];
        #pragma unroll
        for (int m = 0; m < 2; ++m) {
            #pragma unroll
            for (int reg = 0; reg < 4; ++reg) {
                const int wrow = wr * 32 + m * 16 + lk * 4 + reg;
                #pragma unroll
                for (int n = 0; n < 4; ++n) {
                    float y = acc[m][n][reg] + bc[n];
                    if (POST == 1) y = fmaxf(y, 0.f);
                    lds[wrow * LST + wc * 64 + n * 16 + lr] = f2bf(y);
                }
            }
        }
    }
    __syncthreads();

    // ---- read-back: blend (POST==2) + optional coalesced Y1 store (uint4: 16B/lane) ----
    {
        float g = 0.f;
        if (POST == 2) g = 1.0f / (1.0f + __expf(-A.skipp[0]));
        #pragma unroll
        for (int it = 0; it < 4; ++it) {
            int idx = it * 256 + threadIdx.x;   // row = idx>>4, chunk = idx&15
            int row = idx >> 4, c16 = idx & 15;
            int grow = row0 + row;
            if (grow < N) {
                uint4 val = *(const uint4*)&lds[row * LST + c16 * 8];
                if (POST == 2) {
                    uint4 o = *(const uint4*)(A.Old + (size_t)grow * C + c16 * 8);
                    val.x = blend2(val.x, o.x, g);
                    val.y = blend2(val.y, o.y, g);
                    val.z = blend2(val.z, o.z, g);
                    val.w = blend2(val.w, o.w, g);
                    *(uint4*)&lds[row * LST + c16 * 8] = val;
                }
                if (A.Y1)
                    *(uint4*)(A.Y1 + (size_t)grow * C + c16 * 8) = val;
            }
        }
    }
    __syncthreads();

    if (A.nw == 0) return;

    BF8 a2[2][4];
    #pragma unroll
    for (int m = 0; m < 2; ++m)
        #pragma unroll
        for (int kk = 0; kk < 4; ++kk)
            a2[m][kk].v = *(const bf16x8*)&lds[(wr * 32 + m * 16 + lr) * LST + kk * 32 + lk * 8];

    // ---- chained GEMMs: per-wave private staging, NO barriers ----
    for (int w = 0; w < A.nw; ++w) {
        const ushort_t* Wt = A.j[w].w;
        f32x4 c2[2][4];
        #pragma unroll
        for (int m = 0; m < 2; ++m)
            #pragma unroll
            for (int n = 0; n < 4; ++n)
                c2[m][n] = (f32x4){0.f, 0.f, 0.f, 0.f};

        #pragma unroll
        for (int kk = 0; kk < 4; ++kk) {
            #pragma unroll
            for (int n = 0; n < 4; ++n) {
                BF8 b;
                b.v = *(const bf16x8*)(Wt + (size_t)(wc * 64 + n * 16 + lr) * C + kk * 32 + lk * 8);
                c2[0][n] = __builtin_amdgcn_mfma_f32_16x16x32_bf16(a2[0][kk].v, b.v, c2[0][n], 0, 0, 0);
                c2[1][n] = __builtin_amdgcn_mfma_f32_16x16x32_bf16(a2[1][kk].v, b.v, c2[1][n], 0, 0, 0);
            }
        }
        float bc[4];
        #pragma unroll
        for (int n = 0; n < 4; ++n) bc[n] = A.j[w].b[wc * 64 + n * 16 + lr];

        // stage own 32x64 quadrant into this wave's private area
        #pragma unroll
        for (int m = 0; m < 2; ++m) {
            #pragma unroll
            for (int reg = 0; reg < 4; ++reg) {
                const int wrow = m * 16 + lk * 4 + reg;
                #pragma unroll
                for (int n = 0; n < 4; ++n)
                    sh2[wave][wrow * SHST + n * 16 + lr] = f2bf(c2[m][n][reg] + bc[n]);
            }
        }
        // wave-private: LDS writes/reads within a wave are in-order, no barrier needed
        ushort_t* Y = A.j[w].y;
        const int ys = A.j[w].ystride;
        #pragma unroll
        for (int i2 = 0; i2 < 8; ++i2) {
            const int wrow = i2 * 4 + rr2;
            const int grow = rbase + wrow;
            if (grow < N) {
                uint2 val = *(const uint2*)&sh2[wave][wrow * SHST + c4 * 4];
                *(uint2*)(Y + (size_t)grow * ys + wc * 64 + c4 * 4) = val;
            }
        }
    }
}

// ---------- dual-GEMM (for the deferred kv1 projection) ----------
__global__ __launch_bounds__(256, 4) void proj2(
    const ushort_t* __restrict__ Xv,
    const ushort_t* __restrict__ WtA, const float* __restrict__ biasA,
    const ushort_t* __restrict__ WtB, const float* __restrict__ biasB,
    ushort_t* __restrict__ YA, ushort_t* __restrict__ YB, int N)
{
    __shared__ ushort_t sh[4][32 * SHST];
    const int wave = threadIdx.x >> 6, lane = threadIdx.x & 63;
    const int wr = wave >> 1, wc = wave & 1;
    const int lr = lane & 15, lk = lane >> 4;
    const int rr2 = lane >> 4, c4 = lane & 15;

    const int tiles = (N + 63) >> 6;
    for (int t = blockIdx.x; t < tiles; t += gridDim.x) {
        const int rbase = (t << 6) + wr * 32;
        BF8 a[2][4];
        #pragma unroll
        for (int m = 0; m < 2; ++m) {
            const int r = rbase + m * 16 + lr;
            #pragma unroll
            for (int kk = 0; kk < 4; ++kk) {
                if (r < N) {
                    a[m][kk].v = *(const bf16x8*)(Xv + (size_t)r * C + kk * 32 + lk * 8);
                } else {
                    #pragma unroll
                    for (int q = 0; q < 8; ++q) a[m][kk].u[q] = 0;
                }
            }
        }
        #pragma unroll
        for (int w = 0; w < 2; ++w) {
            const ushort_t* Wt = w ? WtB : WtA;
            const float* bias = w ? biasB : biasA;
            ushort_t* Y = w ? YB : YA;
            f32x4 acc[2][4];
            #pragma unroll
            for (int m = 0; m < 2; ++m)
                #pragma unroll
                for (int n = 0; n < 4; ++n)
                    acc[m][n] = (f32x4){0.f, 0.f, 0.f, 0.f};
            #pragma unroll
            for (int kk = 0; kk < 4; ++kk) {
                #pragma unroll
                for (int n = 0; n < 4; ++n) {
                    BF8 b;
                    b.v = *(const bf16x8*)(Wt + (size_t)(wc * 64 + n * 16 + lr) * C + kk * 32 + lk * 8);
                    acc[0][n] = __builtin_amdgcn_mfma_f32_16x16x32_bf16(a[0][kk].v, b.v, acc[0][n], 0, 0, 0);
                    acc[1][n] = __builtin_amdgcn_mfma_f32_16x16x32_bf16(a[1][kk].v, b.v, acc[1][n], 0, 0, 0);
                }
            }
            float bc[4];
            #pragma unroll
            for (int n = 0; n < 4; ++n) bc[n] = bias[wc * 64 + n * 16 + lr];
            #pragma unroll
            for (int m = 0; m < 2; ++m) {
                #pragma unroll
                for (int reg = 0; reg < 4; ++reg) {
                    const int wrow = m * 16 + lk * 4 + reg;
                    #pragma unroll
                    for (int n = 0; n < 4; ++n)
                        sh[wave][wrow * SHST + n * 16 + lr] = f2bf(acc[m][n][reg] + bc[n]);
                }
            }
            #pragma unroll
            for (int i2 = 0; i2 < 8; ++i2) {
                const int wrow = i2 * 4 + rr2;
                const int grow = rbase + wrow;
                if (grow < N) {
                    uint2 val = *(const uint2*)&sh[wave][wrow * SHST + c4 * 4];
                    *(uint2*)(Y + (size_t)grow * (2 * C) + wc * 64 + c4 * 4) = val;
                }
            }
        }
    }
}

// ---------- CSR build ----------
__global__ void hist_k(const int* __restrict__ ei, int E, int* __restrict__ cnt) {
    int i = blockIdx.x * 256 + threadIdx.x;
    if (i < E) atomicAdd(&cnt[ei[E + i]], 1);
}

__global__ __launch_bounds__(256) void scan1(const int* __restrict__ cnt, int n, int* __restrict__ part) {
    __shared__ int sh[256];
    int b = blockIdx.x, t = threadIdx.x;
    int base = b * SC + t * 8;
    int s = 0;
    #pragma unroll
    for (int j = 0; j < 8; ++j) { int i = base + j; if (i < n) s += cnt[i]; }
    sh[t] = s; __syncthreads();
    for (int off = 128; off > 0; off >>= 1) {
        if (t < off) sh[t] += sh[t + off];
        __syncthreads();
    }
    if (t == 0) part[b] = sh[0];
}

__global__ void scan2(int* part, int nb) {
    if (threadIdx.x == 0 && blockIdx.x == 0) {
        int run = 0;
        for (int i = 0; i < nb; ++i) { int v = part[i]; part[i] = run; run += v; }
        part[nb] = run;
    }
}

__global__ __launch_bounds__(256) void scan3(const int* __restrict__ cnt, int n,
                                             const int* __restrict__ part, int* __restrict__ rowptr) {
    __shared__ int sh[256];
    int b = blockIdx.x, t = threadIdx.x;
    int base = b * SC + t * 8;
    int loc[8]; int s = 0;
    #pragma unroll
    for (int j = 0; j < 8; ++j) { int i = base + j; int v = (i < n) ? cnt[i] : 0; s += v; loc[j] = s; }
    sh[t] = s; __syncthreads();
    for (int off = 1; off < 256; off <<= 1) {
        int v = (t >= off) ? sh[t - off] : 0;
        __syncthreads();
        sh[t] += v;
        __syncthreads();
    }
    int excl = (t ? sh[t - 1] : 0) + part[b];
    #pragma unroll
    for (int j = 0; j < 8; ++j) { int i = base + j; if (i < n) rowptr[i + 1] = excl + loc[j]; }
    if (b == 0 && t == 0) rowptr[0] = 0;
}

__global__ void scatter_k(const int* __restrict__ ei, int E, int* __restrict__ wp, int* __restrict__ srcs) {
    int i = blockIdx.x * 256 + threadIdx.x;
    if (i < E) {
        int pos = atomicAdd(&wp[ei[E + i]], 1);
        srcs[pos] = ei[i];
    }
}

// ---------- 32-lane (4 ch/lane) relation accumulate, 2-way edge unrolled ----------
__device__ __forceinline__ void rel_accum32(
    const int* __restrict__ rowptr, const int* __restrict__ srcs, const unsigned* __restrict__ kv,
    int nid, int j, float q0, float q1, float q2, float q3, float rp,
    float& o0, float& o1, float& o2, float& o3)
{
    int beg = rowptr[nid], end = rowptr[nid + 1];
    float denom = 0.f, s0 = 0.f, s1 = 0.f, s2 = 0.f, s3 = 0.f;
    int i = beg;
    for (; i + 2 <= end; i += 2) {
        const unsigned* rA = kv + (size_t)srcs[i] * 128;
        const unsigned* rB = kv + (size_t)srcs[i + 1] * 128;
        uint2 kA = *(const uint2*)(rA + j * 2), kB = *(const uint2*)(rB + j * 2);
        uint2 vA = *(const uint2*)(rA + 64 + j * 2), vB = *(const uint2*)(rB + 64 + j * 2);
        float a0, a1, a2, a3, b0, b1, b2, b3;
        unpack2(kA.x, a0, a1); unpack2(kA.y, a2, a3);
        unpack2(kB.x, b0, b1); unpack2(kB.y, b2, b3);
        float dpA = a0 * q0 + a1 * q1 + a2 * q2 + a3 * q3;
        float dpB = b0 * q0 + b1 * q1 + b2 * q2 + b3 * q3;
        dpA += __shfl_xor(dpA, 1, 8); dpB += __shfl_xor(dpB, 1, 8);
        dpA += __shfl_xor(dpA, 2, 8); dpB += __shfl_xor(dpB, 2, 8);
        dpA += __shfl_xor(dpA, 4, 8); dpB += __shfl_xor(dpB, 4, 8);
        float wA = __expf(dpA * rp), wB = __expf(dpB * rp);
        unpack2(vA.x, a0, a1); unpack2(vA.y, a2, a3);
        unpack2(vB.x, b0, b1); unpack2(vB.y, b2, b3);
        denom += wA + wB;
        s0 += wA * a0 + wB * b0; s1 += wA * a1 + wB * b1;
        s2 += wA * a2 + wB * b2; s3 += wA * a3 + wB * b3;
    }
    if (i < end) {
        const unsigned* rA = kv + (size_t)srcs[i] * 128;
        uint2 kA = *(const uint2*)(rA + j * 2);
        uint2 vA = *(const uint2*)(rA + 64 + j * 2);
        float a0, a1, a2, a3;
        unpack2(kA.x, a0, a1); unpack2(kA.y, a2, a3);
        float dp = a0 * q0 + a1 * q1 + a2 * q2 + a3 * q3;
        dp += __shfl_xor(dp, 1, 8);
        dp += __shfl_xor(dp, 2, 8);
        dp += __shfl_xor(dp, 4, 8);
        float w = __expf(dp * rp);
        unpack2(vA.x, a0, a1); unpack2(vA.y, a2, a3);
        denom += w;
        s0 += w * a0; s1 += w * a1; s2 += w * a2; s3 += w * a3;
    }
    float r = 1.0f / (denom + 1e-16f);
    o0 += s0 * r; o1 += s1 * r; o2 += s2 * r; o3 += s3 * r;
}

// ---------- visit-dst edges: relations 0 and 2 merged ----------
__global__ __launch_bounds__(256) void edge_vis(
    const int* __restrict__ rp0, const int* __restrict__ s0, const unsigned* __restrict__ kv0,
    const int* __restrict__ rp2, const int* __restrict__ s2, const unsigned* __restrict__ kv2,
    const unsigned* __restrict__ qv, const float* __restrict__ relPl,
    unsigned* __restrict__ agg, int Nd)
{
    int nid = (int)((blockIdx.x * 256u + threadIdx.x) >> 5);
    int j = threadIdx.x & 31;
    if (nid >= Nd) return;
    int head = j >> 3;
    uint2 q2 = *(const uint2*)(qv + (size_t)nid * 64 + j * 2);
    float q0, q1, qq2, q3;
    unpack2(q2.x, q0, q1); unpack2(q2.y, qq2, q3);
    float rpA = relPl[0 * H + head] * RSC;
    float rpB = relPl[2 * H + head] * RSC;
    float o0 = 0.f, o1 = 0.f, o2 = 0.f, o3 = 0.f;
    rel_accum32(rp0, s0, kv0, nid, j, q0, q1, qq2, q3, rpA, o0, o1, o2, o3);
    rel_accum32(rp2, s2, kv2, nid, j, q0, q1, qq2, q3, rpB, o0, o1, o2, o3);
    uint2 o; o.x = pack2(o0, o1); o.y = pack2(o2, o3);
    *(uint2*)(agg + (size_t)nid * 64 + j * 2) = o;
}

// ---------- code-dst edges: relation 1 (agg may alias qv: own-row read precedes write) ----------
__global__ __launch_bounds__(256) void edge_code(
    const int* __restrict__ rp1, const int* __restrict__ s1, const unsigned* __restrict__ kv1,
    const unsigned* __restrict__ qv, const float* __restrict__ relPh,
    unsigned* __restrict__ agg, int Nd)
{
    int nid = (int)((blockIdx.x * 256u + threadIdx.x) >> 5);
    int j = threadIdx.x & 31;
    if (nid >= Nd) return;
    int head = j >> 3;
    uint2 q2 = *(const uint2*)(qv + (size_t)nid * 64 + j * 2);
    float q0, q1, qq2, q3;
    unpack2(q2.x, q0, q1); unpack2(q2.y, qq2, q3);
    float rp = relPh[head] * RSC;
    float o0 = 0.f, o1 = 0.f, o2 = 0.f, o3 = 0.f;
    rel_accum32(rp1, s1, kv1, nid, j, q0, q1, qq2, q3, rp, o0, o1, o2, o3);
    uint2 o; o.x = pack2(o0, o1); o.y = pack2(o2, o3);
    *(uint2*)(agg + (size_t)nid * 64 + j * 2) = o;
}

// ---------- final: layer-1 visit update fused with patient gather + linear ----------
__global__ void final_fused(const ushort_t* __restrict__ aggV, const ushort_t* __restrict__ xs0,
                            const int* __restrict__ slices,
                            const float* __restrict__ aWp, const float* __restrict__ abp,
                            const float* __restrict__ skipp,
                            const float* __restrict__ Wl, const float* __restrict__ bl,
                            float* __restrict__ out)
{
    __shared__ float ga[C];
    __shared__ float xr[C];
    int b = blockIdx.x, o = threadIdx.x;
    int row = slices[b + 1] - 1;
    ga[o] = gelu_t(bf2f(aggV[(size_t)row * C + o]));
    __syncthreads();
    float y = abp[o];
    #pragma unroll 4
    for (int c = 0; c < C; ++c) y += ga[c] * aWp[c * C + o];
    float g = 1.0f / (1.0f + __expf(-skipp[0]));
    xr[o] = g * y + (1.f - g) * bf2f(xs0[(size_t)row * C + o]);
    __syncthreads();
    float acc = bl[o];
    #pragma unroll 4
    for (int c = 0; c < C; ++c) acc += xr[c] * Wl[c * C + o];
    out[(size_t)b * C + o] = acc;
}

extern "C" void kernel_launch(void* const* d_in, const int* in_sizes, int n_in,
                              void* d_out, int out_size, void* d_ws, size_t ws_size,
                              hipStream_t stream)
{
    (void)n_in;
    const float* x_visit = (const float*)d_in[0];
    const float* x_code  = (const float*)d_in[1];
    const int* slices    = (const int*)d_in[5];
    const float* lin0_W  = (const float*)d_in[6];
    const float* lin0_b  = (const float*)d_in[7];
    const float* kW  = (const float*)d_in[8];
    const float* kb  = (const float*)d_in[9];
    const float* qW  = (const float*)d_in[10];
    const float* qb  = (const float*)d_in[11];
    const float* vW  = (const float*)d_in[12];
    const float* vb  = (const float*)d_in[13];
    const float* aW  = (const float*)d_in[14];
    const float* ab  = (const float*)d_in[15];
    const float* skip = (const float*)d_in[16];
    const float* relA = (const float*)d_in[17];
    const float* relM = (const float*)d_in[18];
    const float* relP = (const float*)d_in[19];
    const float* linW = (const float*)d_in[20];
    const float* linb = (const float*)d_in[21];

    const int NV = in_sizes[0] / C;
    const int NC = in_sizes[1] / C;
    const int NN = NV > NC ? NV : NC;
    const int B = in_sizes[5] - 1;

    const int* eptr[3] = {(const int*)d_in[2], (const int*)d_in[3], (const int*)d_in[4]};
    const int Ecnt[3] = {in_sizes[2] / 2, in_sizes[3] / 2, in_sizes[4] / 2};
    const int Ndrel[3] = {NV, NC, NV};

    // ---- workspace plan with aliased regions; fits measured ~359.37 MB ----
    size_t off = 0;
    auto AL = [&](size_t bytes) { size_t c = off; off += (bytes + 255) & ~(size_t)255; return c; };
    size_t o_xs0  = AL((size_t)NV * C * 2);
    size_t o_xs1  = AL((size_t)NC * C * 2);
    size_t o_q0   = AL((size_t)NV * C * 2);
    size_t o_q1   = AL((size_t)NC * C * 2);   // q1; re-used in-place as aggC after l=0 edge_code
    size_t o_aggV = AL((size_t)NV * C * 2);
    size_t o_rp[3], o_srcs[3];
    for (int e = 0; e < 3; ++e) {
        o_rp[e]   = AL(((size_t)Ndrel[e] + 1) * 4);
        o_srcs[e] = AL((size_t)Ecnt[e] * 4);
    }
    size_t o_wp   = AL(((size_t)NN + 1) * 4);
    size_t o_part = AL(4096);
    size_t o_fw   = AL((size_t)12 * (CC + C) * 4);
    size_t o_wt   = AL((size_t)22 * CC * 2);
    size_t o_RA   = AL((size_t)NC * 2 * C * 2);   // kv0, later kv1
    size_t o_RB   = AL((size_t)NV * 2 * C * 2);   // kv2 only
    size_t total = off;

    if (ws_size < total) {
        float v = 30.0f + (float)((double)ws_size * 1e-9);
        diag_fill<<<(out_size + 255) / 256, 256, 0, stream>>>((float*)d_out, out_size, v);
        return;
    }

    char* base = (char*)d_ws;
    ushort_t* xs0  = (ushort_t*)(base + o_xs0);
    ushort_t* xs1  = (ushort_t*)(base + o_xs1);
    ushort_t* q0   = (ushort_t*)(base + o_q0);
    ushort_t* q1   = (ushort_t*)(base + o_q1);
    ushort_t* aggV = (ushort_t*)(base + o_aggV);
    ushort_t* aggC = q1;   // alias: q1 dead after l=0 edge_code (in-place own-row write)
    int* rp_[3]; int* srcs_[3];
    for (int e = 0; e < 3; ++e) { rp_[e] = (int*)(base + o_rp[e]); srcs_[e] = (int*)(base + o_srcs[e]); }
    int* wp   = (int*)(base + o_wp);
    int* part = (int*)(base + o_part);
    float* fw = (float*)(base + o_fw);
    ushort_t* wt = (ushort_t*)(base + o_wt);
    ushort_t* kv0  = (ushort_t*)(base + o_RA);
    ushort_t* kv1  = (ushort_t*)(base + o_RA);
    ushort_t* kv2  = (ushort_t*)(base + o_RB);

    auto wt_q = [&](int l, int t) { return wt + (size_t)(2 + l * 2 + t) * CC; };
    auto wt_a = [&](int l, int t) { return wt + (size_t)(6 + l * 2 + t) * CC; };
    auto wt_f = [&](int le, int which) { return wt + (size_t)(10 + le * 2 + which) * CC; };
    auto fb   = [&](int le, int which) { return fw + (size_t)(le * 2 + which) * (CC + C) + CC; };

    // 1) weight prep
    fuse_weights<<<12, 256, 0, stream>>>(kW, kb, vW, vb, relA, relM, fw);
    trans_w<<<22, 256, 0, stream>>>(lin0_W, qW, aW, fw, wt);

    // 2) CSR build per relation
    for (int e = 0; e < 3; ++e) {
        int Nd = Ndrel[e], E = Ecnt[e];
        int nb = (Nd + SC - 1) / SC;
        hipMemsetAsync(wp, 0, (size_t)Nd * 4, stream);
        hist_k<<<(E + 255) / 256, 256, 0, stream>>>(eptr[e], E, wp);
        scan1<<<nb, 256, 0, stream>>>(wp, Nd, part);
        scan2<<<1, 64, 0, stream>>>(part, nb);
        scan3<<<nb, 256, 0, stream>>>(wp, Nd, part, rp_[e]);
        hipMemcpyAsync(wp, rp_[e], (size_t)Nd * 4, hipMemcpyDeviceToDevice, stream);
        scatter_k<<<(E + 255) / 256, 256, 0, stream>>>(eptr[e], E, wp, srcs_[e]);
    }

    const int tilesV = (NV + 63) / 64, tilesC = (NC + 63) / 64;
    unsigned gV = (unsigned)(((size_t)NV * 32 + 255) / 256);
    unsigned gC = (unsigned)(((size_t)NC * 32 + 255) / 256);

    // ---- layer 0: combined input-proj + projections (no aliasing) ----
    {
        FusedArgs aC = {}, aV = {};
        aC.X = x_code; aC.W1 = wt + CC; aC.b1 = lin0_b + C; aC.Y1 = xs1;
        aC.N = NC; aC.nw = 3;
        aC.j[0] = {wt_q(0, 1), qb + 1 * C, q1, C};
        aC.j[1] = {wt_f(0, 0), fb(0, 0), kv0, 2 * C};
        aC.j[2] = {wt_f(0, 1), fb(0, 1), kv0 + C, 2 * C};
        aV.X = x_visit; aV.W1 = wt; aV.b1 = lin0_b; aV.Y1 = xs0;
        aV.N = NV; aV.nw = 3;
        aV.j[0] = {wt_q(0, 0), qb + 0 * C, q0, C};
        aV.j[1] = {wt_f(2, 0), fb(2, 0), kv2, 2 * C};
        aV.j[2] = {wt_f(2, 1), fb(2, 1), kv2 + C, 2 * C};
        fusedProj<0, 0, 1><<<(unsigned)(tilesC + tilesV), 256, 0, stream>>>(aC, aV, tilesC);
    }
    edge_vis<<<gV, 256, 0, stream>>>(
        rp_[0], srcs_[0], (const unsigned*)kv0,
        rp_[2], srcs_[2], (const unsigned*)kv2,
        (const unsigned*)q0, relP + 0 * 3 * H, (unsigned*)aggV, NV);
    proj2<<<(unsigned)tilesV, 256, 0, stream>>>(
        xs0, wt_f(1, 0), fb(1, 0), wt_f(1, 1), fb(1, 1), kv1, kv1 + C, NV);
    // aggC written in-place over q1 (own-row read precedes write)
    edge_code<<<gC, 256, 0, stream>>>(
        rp_[1], srcs_[1], (const unsigned*)kv1,
        (const unsigned*)q1, relP + (size_t)1 * H, (unsigned*)aggC, NC);

    // ---- layer 1: combined update+projection launch (aggC in q1-space, no R_B conflict) ----
    {
        FusedArgs aC = {}, aV = {};
        // code side: update (xs1 store DEAD -> Y1=null) + chained kv0
        aC.X = aggC; aC.W1 = wt_a(0, 1); aC.b1 = ab + 1 * C; aC.Y1 = nullptr;
        aC.Old = xs1; aC.skipp = skip + 1; aC.N = NC; aC.nw = 2;
        aC.j[0] = {wt_f(3, 0), fb(3, 0), kv0, 2 * C};
        aC.j[1] = {wt_f(3, 1), fb(3, 1), kv0 + C, 2 * C};
        aC.j[2] = {nullptr, nullptr, nullptr, 0};
        // visit side: update + chained {q0, kv2}
        aV.X = aggV; aV.W1 = wt_a(0, 0); aV.b1 = ab + 0 * C; aV.Y1 = xs0;
        aV.Old = xs0; aV.skipp = skip + 0; aV.N = NV; aV.nw = 3;
        aV.j[0] = {wt_q(1, 0), qb + 2 * C, q0, C};
        aV.j[1] = {wt_f(5, 0), fb(5, 0), kv2, 2 * C};
        aV.j[2] = {wt_f(5, 1), fb(5, 1), kv2 + C, 2 * C};
        fusedProj<1, 1, 2><<<(unsigned)(tilesC + tilesV), 256, 0, stream>>>(aC, aV, tilesC);
    }
    edge_vis<<<gV, 256, 0, stream>>>(
        rp_[0], srcs_[0], (const unsigned*)kv0,
        rp_[2], srcs_[2], (const unsigned*)kv2,
        (const unsigned*)q0, relP + (size_t)3 * H, (unsigned*)aggV, NV);

    // final: layer-1 visit update + patient gather + linear (only 1024 rows needed)
    final_fused<<<B, 128, 0, stream>>>(
        aggV, xs0, slices, aW + (size_t)2 * CC, ab + 2 * C, skip + 2,
        linW, linb, (float*)d_out);
}

// Round 18
// 895.588 us; speedup vs baseline: 1.0079x; 1.0079x over previous
//
#include <hip/hip_runtime.h>
#include <math.h>

#define H 4
#define D 32
#define C 128
#define CC (C * C)
#define SC 2048
#define LST 136   // LDS row stride (shorts); 272B = multiple of 16 -> aligned b128 reads
#define SHST 68
#define RSC 0.17677669529663687f

typedef unsigned short ushort_t;
typedef __attribute__((ext_vector_type(8))) short bf16x8;
typedef __attribute__((ext_vector_type(4))) float f32x4;

union BF8 { bf16x8 v; ushort_t u[8]; };

// ---------- helpers ----------
__device__ __forceinline__ float bf2f(ushort_t u) {
    return __uint_as_float(((unsigned)u) << 16);
}
__device__ __forceinline__ ushort_t f2bf(float f) {
    unsigned u = __float_as_uint(f);
    u += 0x7fffu + ((u >> 16) & 1u);
    return (ushort_t)(u >> 16);
}
__device__ __forceinline__ void unpack2(unsigned w, float& a, float& b) {
    a = __uint_as_float(w << 16);
    b = __uint_as_float(w & 0xffff0000u);
}
__device__ __forceinline__ unsigned pack2(float a, float b) {
    return ((unsigned)f2bf(b) << 16) | (unsigned)f2bf(a);
}
__device__ __forceinline__ unsigned blend2(unsigned yw, unsigned ow, float g) {
    float y0, y1, o0, o1;
    unpack2(yw, y0, y1); unpack2(ow, o0, o1);
    return pack2(g * y0 + (1.f - g) * o0, g * y1 + (1.f - g) * o1);
}
__device__ __forceinline__ float gelu_t(float x) {
    float z = 0.7978845608028654f * (x + 0.044715f * x * x * x);
    float t = 1.0f - 2.0f / (__expf(2.0f * z) + 1.0f);
    return 0.5f * x * (1.0f + t);
}

// ---------- diag ----------
__global__ void diag_fill(float* out, int n, float v) {
    int i = blockIdx.x * 256 + threadIdx.x;
    if (i < n) out[i] = v;
}

// ---------- fused relation weights (fp32): W' = W @ blockdiag(rel) ----------
__global__ void fuse_weights(const float* __restrict__ kW, const float* __restrict__ kb,
                             const float* __restrict__ vW, const float* __restrict__ vb,
                             const float* __restrict__ relA, const float* __restrict__ relM,
                             float* __restrict__ fw)
{
    int bid = blockIdx.x;      // 0..11
    int le = bid >> 1;         // l*3+e
    int which = bid & 1;       // 0 = k/relA, 1 = v/relM
    int l = le / 3, e = le % 3;
    const int est[3] = {1, 0, 0};
    int st = est[e];
    const float* Wsrc = (which ? vW : kW) + (size_t)(l * 2 + st) * CC;
    const float* bsrc = (which ? vb : kb) + (size_t)(l * 2 + st) * C;
    const float* rel  = (which ? relM : relA) + (size_t)(l * 3 + e) * H * D * D;
    float* out = fw + (size_t)(le * 2 + which) * (CC + C);

    __shared__ float rsh[H * D * D];
    for (int i = threadIdx.x; i < H * D * D; i += 256) rsh[i] = rel[i];
    __syncthreads();

    for (int i = threadIdx.x; i < CC; i += 256) {
        int c = i >> 7, hf = i & 127, h = hf >> 5, f = hf & 31;
        float acc = 0.f;
        #pragma unroll
        for (int d = 0; d < D; ++d)
            acc += Wsrc[c * C + h * D + d] * rsh[h * D * D + d * D + f];
        out[i] = acc;
    }
    for (int i = threadIdx.x; i < C; i += 256) {
        int h = i >> 5, f = i & 31;
        float acc = 0.f;
        #pragma unroll
        for (int d = 0; d < D; ++d)
            acc += bsrc[h * D + d] * rsh[h * D * D + d * D + f];
        out[CC + i] = acc;
    }
}

// ---------- transpose all weights to bf16 Wt[n][k] ----------
__global__ void trans_w(const float* __restrict__ lin0_W, const float* __restrict__ qW,
                        const float* __restrict__ aW, const float* __restrict__ fw,
                        ushort_t* __restrict__ wt)
{
    int id = blockIdx.x;
    const float* src;
    if (id < 2)       src = lin0_W + (size_t)id * CC;
    else if (id < 6)  src = qW + (size_t)(id - 2) * CC;
    else if (id < 10) src = aW + (size_t)(id - 6) * CC;
    else              src = fw + (size_t)(id - 10) * (CC + C);
    ushort_t* dst = wt + (size_t)id * CC;
    for (int i = threadIdx.x; i < CC; i += 256) {
        int n = i >> 7, k = i & 127;
        dst[i] = f2bf(src[k * C + n]);
    }
}

// ---------- fused two-stage MFMA kernel (round-16 proven structure) ----------
struct WJob { const ushort_t* w; const float* b; ushort_t* y; int ystride; };
struct FusedArgs {
    const void* X; const ushort_t* W1; const float* b1; ushort_t* Y1;  // Y1 may be null (skip store)
    const ushort_t* Old; const float* skipp; int N; int nw;
    WJob j[3];
};

template <int INTYPE, int PRE, int POST>
__global__ __launch_bounds__(256, 4) void fusedProj(FusedArgs A0, FusedArgs A1, int tiles0)
{
    __shared__ ushort_t lds[64 * LST];   // 17408 B
    const bool sel0 = ((int)blockIdx.x < tiles0);
    const FusedArgs& A = sel0 ? A0 : A1;
    const int t = sel0 ? (int)blockIdx.x : (int)blockIdx.x - tiles0;
    const int N = A.N;
    const int wave = threadIdx.x >> 6, lane = threadIdx.x & 63;
    const int wr = wave >> 1, wc = wave & 1;
    const int lr = lane & 15, lk = lane >> 4;
    const int row0 = t << 6;
    const int rbase = row0 + wr * 32;

    BF8 a[2][4];
    #pragma unroll
    for (int m = 0; m < 2; ++m) {
        const int r = rbase + m * 16 + lr;
        #pragma unroll
        for (int kk = 0; kk < 4; ++kk) {
            if (INTYPE == 0) {
                float vv[8];
                if (r < N) {
                    const float* p = (const float*)A.X + (size_t)r * C + kk * 32 + lk * 8;
                    float4 u0 = *(const float4*)p;
                    float4 u1 = *(const float4*)(p + 4);
                    vv[0] = u0.x; vv[1] = u0.y; vv[2] = u0.z; vv[3] = u0.w;
                    vv[4] = u1.x; vv[5] = u1.y; vv[6] = u1.z; vv[7] = u1.w;
                } else {
                    #pragma unroll
                    for (int q = 0; q < 8; ++q) vv[q] = 0.f;
                }
                #pragma unroll
                for (int q = 0; q < 8; ++q) a[m][kk].u[q] = f2bf(PRE ? gelu_t(vv[q]) : vv[q]);
            } else {
                if (r < N) {
                    a[m][kk].v = *(const bf16x8*)((const ushort_t*)A.X + (size_t)r * C + kk * 32 + lk * 8);
                    if (PRE) {
                        #pragma unroll
                        for (int q = 0; q < 8; ++q) a[m][kk].u[q] = f2bf(gelu_t(bf2f(a[m][kk].u[q])));
                    }
                } else {
                    #pragma unroll
                    for (int q = 0; q < 8; ++q) a[m][kk].u[q] = 0;
                }
            }
        }
    }

    // ---- GEMM1 ----
    {
        f32x4 acc[2][4];
        #pragma unroll
        for (int m = 0; m < 2; ++m)
            #pragma unroll
            for (int n = 0; n < 4; ++n)
                acc[m][n] = (f32x4){0.f, 0.f, 0.f, 0.f};

        #pragma unroll
        for (int kk = 0; kk < 4; ++kk) {
            #pragma unroll
            for (int n = 0; n < 4; ++n) {
                BF8 b;
                b.v = *(const bf16x8*)(A.W1 + (size_t)(wc * 64 + n * 16 + lr) * C + kk * 32 + lk * 8);
                acc[0][n] = __builtin_amdgcn_mfma_f32_16x16x32_bf16(a[0][kk].v, b.v, acc[0][n], 0, 0, 0);
                acc[1][n] = __builtin_amdgcn_mfma_f32_16x16x32_bf16(a[1][kk].v, b.v, acc[1][n], 0, 0, 0);
            }
        }

        float bc[4];
        #pragma unroll
        for (int n = 0; n < 4; ++n) bc[n] = A.b1[wc * 64 + n * 16 + lr];
        #pragma unroll
        for (int m = 0; m < 2; ++m) {
            #pragma unroll
            for (int reg = 0; reg < 4; ++reg) {
                const int wrow = wr * 32 + m * 16 + lk * 4 + reg;
                #pragma unroll
                for (int n = 0; n < 4; ++n) {
                    float y = acc[m][n][reg] + bc[n];
                    if (POST == 1) y = fmaxf(y, 0.f);
                    lds[wrow * LST + wc * 64 + n * 16 + lr] = f2bf(y);
                }
            }
        }
    }
    __syncthreads();

    // ---- read-back: blend (POST==2) + optional coalesced Y1 store (uint4: 16B/lane) ----
    {
        float g = 0.f;
        if (POST == 2) g = 1.0f / (1.0f + __expf(-A.skipp[0]));
        #pragma unroll
        for (int it = 0; it < 4; ++it) {
            int idx = it * 256 + threadIdx.x;   // row = idx>>4, chunk = idx&15
            int row = idx >> 4, c16 = idx & 15;
            int grow = row0 + row;
            if (grow < N) {
                uint4 val = *(const uint4*)&lds[row * LST + c16 * 8];
                if (POST == 2) {
                    uint4 o = *(const uint4*)(A.Old + (size_t)grow * C + c16 * 8);
                    val.x = blend2(val.x, o.x, g);
                    val.y = blend2(val.y, o.y, g);
                    val.z = blend2(val.z, o.z, g);
                    val.w = blend2(val.w, o.w, g);
                    *(uint4*)&lds[row * LST + c16 * 8] = val;
                }
                if (A.Y1)
                    *(uint4*)(A.Y1 + (size_t)grow * C + c16 * 8) = val;
            }
        }
    }
    __syncthreads();

    if (A.nw == 0) return;

    BF8 a2[2][4];
    #pragma unroll
    for (int m = 0; m < 2; ++m)
        #pragma unroll
        for (int kk = 0; kk < 4; ++kk)
            a2[m][kk].v = *(const bf16x8*)&lds[(wr * 32 + m * 16 + lr) * LST + kk * 32 + lk * 8];

    for (int w = 0; w < A.nw; ++w) {
        const ushort_t* Wt = A.j[w].w;
        f32x4 c2[2][4];
        #pragma unroll
        for (int m = 0; m < 2; ++m)
            #pragma unroll
            for (int n = 0; n < 4; ++n)
                c2[m][n] = (f32x4){0.f, 0.f, 0.f, 0.f};

        #pragma unroll
        for (int kk = 0; kk < 4; ++kk) {
            #pragma unroll
            for (int n = 0; n < 4; ++n) {
                BF8 b;
                b.v = *(const bf16x8*)(Wt + (size_t)(wc * 64 + n * 16 + lr) * C + kk * 32 + lk * 8);
                c2[0][n] = __builtin_amdgcn_mfma_f32_16x16x32_bf16(a2[0][kk].v, b.v, c2[0][n], 0, 0, 0);
                c2[1][n] = __builtin_amdgcn_mfma_f32_16x16x32_bf16(a2[1][kk].v, b.v, c2[1][n], 0, 0, 0);
            }
        }
        float bc[4];
        #pragma unroll
        for (int n = 0; n < 4; ++n) bc[n] = A.j[w].b[wc * 64 + n * 16 + lr];

        __syncthreads();
        #pragma unroll
        for (int m = 0; m < 2; ++m) {
            #pragma unroll
            for (int reg = 0; reg < 4; ++reg) {
                const int wrow = wr * 32 + m * 16 + lk * 4 + reg;
                #pragma unroll
                for (int n = 0; n < 4; ++n)
                    lds[wrow * LST + wc * 64 + n * 16 + lr] = f2bf(c2[m][n][reg] + bc[n]);
            }
        }
        __syncthreads();

        ushort_t* Y = A.j[w].y;
        const int ys = A.j[w].ystride;
        #pragma unroll
        for (int it = 0; it < 4; ++it) {
            int idx = it * 256 + threadIdx.x;
            int row = idx >> 4, c16 = idx & 15;
            int grow = row0 + row;
            if (grow < N) {
                uint4 val = *(const uint4*)&lds[row * LST + c16 * 8];
                *(uint4*)(Y + (size_t)grow * ys + c16 * 8) = val;
            }
        }
    }
}

// ---------- dual-GEMM (for the deferred kv1 projection) ----------
__global__ __launch_bounds__(256, 4) void proj2(
    const ushort_t* __restrict__ Xv,
    const ushort_t* __restrict__ WtA, const float* __restrict__ biasA,
    const ushort_t* __restrict__ WtB, const float* __restrict__ biasB,
    ushort_t* __restrict__ YA, ushort_t* __restrict__ YB, int N)
{
    __shared__ ushort_t sh[4][32 * SHST];
    const int wave = threadIdx.x >> 6, lane = threadIdx.x & 63;
    const int wr = wave >> 1, wc = wave & 1;
    const int lr = lane & 15, lk = lane >> 4;
    const int rr2 = lane >> 4, c4 = lane & 15;

    const int tiles = (N + 63) >> 6;
    for (int t = blockIdx.x; t < tiles; t += gridDim.x) {
        const int rbase = (t << 6) + wr * 32;
        BF8 a[2][4];
        #pragma unroll
        for (int m = 0; m < 2; ++m) {
            const int r = rbase + m * 16 + lr;
            #pragma unroll
            for (int kk = 0; kk < 4; ++kk) {
                if (r < N) {
                    a[m][kk].v = *(const bf16x8*)(Xv + (size_t)r * C + kk * 32 + lk * 8);
                } else {
                    #pragma unroll
                    for (int q = 0; q < 8; ++q) a[m][kk].u[q] = 0;
                }
            }
        }
        #pragma unroll
        for (int w = 0; w < 2; ++w) {
            const ushort_t* Wt = w ? WtB : WtA;
            const float* bias = w ? biasB : biasA;
            ushort_t* Y = w ? YB : YA;
            f32x4 acc[2][4];
            #pragma unroll
            for (int m = 0; m < 2; ++m)
                #pragma unroll
                for (int n = 0; n < 4; ++n)
                    acc[m][n] = (f32x4){0.f, 0.f, 0.f, 0.f};
            #pragma unroll
            for (int kk = 0; kk < 4; ++kk) {
                #pragma unroll
                for (int n = 0; n < 4; ++n) {
                    BF8 b;
                    b.v = *(const bf16x8*)(Wt + (size_t)(wc * 64 + n * 16 + lr) * C + kk * 32 + lk * 8);
                    acc[0][n] = __builtin_amdgcn_mfma_f32_16x16x32_bf16(a[0][kk].v, b.v, acc[0][n], 0, 0, 0);
                    acc[1][n] = __builtin_amdgcn_mfma_f32_16x16x32_bf16(a[1][kk].v, b.v, acc[1][n], 0, 0, 0);
                }
            }
            float bc[4];
            #pragma unroll
            for (int n = 0; n < 4; ++n) bc[n] = bias[wc * 64 + n * 16 + lr];
            #pragma unroll
            for (int m = 0; m < 2; ++m) {
                #pragma unroll
                for (int reg = 0; reg < 4; ++reg) {
                    const int wrow = m * 16 + lk * 4 + reg;
                    #pragma unroll
                    for (int n = 0; n < 4; ++n)
                        sh[wave][wrow * SHST + n * 16 + lr] = f2bf(acc[m][n][reg] + bc[n]);
                }
            }
            #pragma unroll
            for (int i2 = 0; i2 < 8; ++i2) {
                const int wrow = i2 * 4 + rr2;
                const int grow = rbase + wrow;
                if (grow < N) {
                    uint2 val = *(const uint2*)&sh[wave][wrow * SHST + c4 * 4];
                    *(uint2*)(Y + (size_t)grow * (2 * C) + wc * 64 + c4 * 4) = val;
                }
            }
        }
    }
}

// ---------- CSR build ----------
__global__ void hist_k(const int* __restrict__ ei, int E, int* __restrict__ cnt) {
    int i = blockIdx.x * 256 + threadIdx.x;
    if (i < E) atomicAdd(&cnt[ei[E + i]], 1);
}

__global__ __launch_bounds__(256) void scan1(const int* __restrict__ cnt, int n, int* __restrict__ part) {
    __shared__ int sh[256];
    int b = blockIdx.x, t = threadIdx.x;
    int base = b * SC + t * 8;
    int s = 0;
    #pragma unroll
    for (int j = 0; j < 8; ++j) { int i = base + j; if (i < n) s += cnt[i]; }
    sh[t] = s; __syncthreads();
    for (int off = 128; off > 0; off >>= 1) {
        if (t < off) sh[t] += sh[t + off];
        __syncthreads();
    }
    if (t == 0) part[b] = sh[0];
}

__global__ void scan2(int* part, int nb) {
    if (threadIdx.x == 0 && blockIdx.x == 0) {
        int run = 0;
        for (int i = 0; i < nb; ++i) { int v = part[i]; part[i] = run; run += v; }
        part[nb] = run;
    }
}

__global__ __launch_bounds__(256) void scan3(const int* __restrict__ cnt, int n,
                                             const int* __restrict__ part, int* __restrict__ rowptr) {
    __shared__ int sh[256];
    int b = blockIdx.x, t = threadIdx.x;
    int base = b * SC + t * 8;
    int loc[8]; int s = 0;
    #pragma unroll
    for (int j = 0; j < 8; ++j) { int i = base + j; int v = (i < n) ? cnt[i] : 0; s += v; loc[j] = s; }
    sh[t] = s; __syncthreads();
    for (int off = 1; off < 256; off <<= 1) {
        int v = (t >= off) ? sh[t - off] : 0;
        __syncthreads();
        sh[t] += v;
        __syncthreads();
    }
    int excl = (t ? sh[t - 1] : 0) + part[b];
    #pragma unroll
    for (int j = 0; j < 8; ++j) { int i = base + j; if (i < n) rowptr[i + 1] = excl + loc[j]; }
    if (b == 0 && t == 0) rowptr[0] = 0;
}

__global__ void scatter_k(const int* __restrict__ ei, int E, int* __restrict__ wp, int* __restrict__ srcs) {
    int i = blockIdx.x * 256 + threadIdx.x;
    if (i < E) {
        int pos = atomicAdd(&wp[ei[E + i]], 1);
        srcs[pos] = ei[i];
    }
}

// ---------- 32-lane (4 ch/lane) relation accumulate, 4-way edge unrolled ----------
__device__ __forceinline__ void rel_accum32(
    const int* __restrict__ rowptr, const int* __restrict__ srcs, const unsigned* __restrict__ kv,
    int nid, int j, float q0, float q1, float q2, float q3, float rp,
    float& o0, float& o1, float& o2, float& o3)
{
    int beg = rowptr[nid], end = rowptr[nid + 1];
    float denom = 0.f, s0 = 0.f, s1 = 0.f, s2 = 0.f, s3 = 0.f;
    int i = beg;
    for (; i + 4 <= end; i += 4) {
        const unsigned* r0 = kv + (size_t)srcs[i] * 128;
        const unsigned* r1 = kv + (size_t)srcs[i + 1] * 128;
        const unsigned* r2 = kv + (size_t)srcs[i + 2] * 128;
        const unsigned* r3 = kv + (size_t)srcs[i + 3] * 128;
        uint2 k0 = *(const uint2*)(r0 + j * 2), k1 = *(const uint2*)(r1 + j * 2);
        uint2 k2w = *(const uint2*)(r2 + j * 2), k3 = *(const uint2*)(r3 + j * 2);
        uint2 v0 = *(const uint2*)(r0 + 64 + j * 2), v1 = *(const uint2*)(r1 + 64 + j * 2);
        uint2 v2 = *(const uint2*)(r2 + 64 + j * 2), v3 = *(const uint2*)(r3 + 64 + j * 2);
        float a0, a1, a2, a3;
        unpack2(k0.x, a0, a1); unpack2(k0.y, a2, a3);
        float dp0 = a0 * q0 + a1 * q1 + a2 * q2 + a3 * q3;
        unpack2(k1.x, a0, a1); unpack2(k1.y, a2, a3);
        float dp1 = a0 * q0 + a1 * q1 + a2 * q2 + a3 * q3;
        unpack2(k2w.x, a0, a1); unpack2(k2w.y, a2, a3);
        float dp2 = a0 * q0 + a1 * q1 + a2 * q2 + a3 * q3;
        unpack2(k3.x, a0, a1); unpack2(k3.y, a2, a3);
        float dp3 = a0 * q0 + a1 * q1 + a2 * q2 + a3 * q3;
        dp0 += __shfl_xor(dp0, 1, 8); dp1 += __shfl_xor(dp1, 1, 8);
        dp2 += __shfl_xor(dp2, 1, 8); dp3 += __shfl_xor(dp3, 1, 8);
        dp0 += __shfl_xor(dp0, 2, 8); dp1 += __shfl_xor(dp1, 2, 8);
        dp2 += __shfl_xor(dp2, 2, 8); dp3 += __shfl_xor(dp3, 2, 8);
        dp0 += __shfl_xor(dp0, 4, 8); dp1 += __shfl_xor(dp1, 4, 8);
        dp2 += __shfl_xor(dp2, 4, 8); dp3 += __shfl_xor(dp3, 4, 8);
        float w0 = __expf(dp0 * rp), w1 = __expf(dp1 * rp);
        float w2 = __expf(dp2 * rp), w3 = __expf(dp3 * rp);
        denom += (w0 + w1) + (w2 + w3);
        unpack2(v0.x, a0, a1); unpack2(v0.y, a2, a3);
        s0 += w0 * a0; s1 += w0 * a1; s2 += w0 * a2; s3 += w0 * a3;
        unpack2(v1.x, a0, a1); unpack2(v1.y, a2, a3);
        s0 += w1 * a0; s1 += w1 * a1; s2 += w1 * a2; s3 += w1 * a3;
        unpack2(v2.x, a0, a1); unpack2(v2.y, a2, a3);
        s0 += w2 * a0; s1 += w2 * a1; s2 += w2 * a2; s3 += w2 * a3;
        unpack2(v3.x, a0, a1); unpack2(v3.y, a2, a3);
        s0 += w3 * a0; s1 += w3 * a1; s2 += w3 * a2; s3 += w3 * a3;
    }
    for (; i + 2 <= end; i += 2) {
        const unsigned* rA = kv + (size_t)srcs[i] * 128;
        const unsigned* rB = kv + (size_t)srcs[i + 1] * 128;
        uint2 kA = *(const uint2*)(rA + j * 2), kB = *(const uint2*)(rB + j * 2);
        uint2 vA = *(const uint2*)(rA + 64 + j * 2), vB = *(const uint2*)(rB + 64 + j * 2);
        float a0, a1, a2, a3, b0, b1, b2, b3;
        unpack2(kA.x, a0, a1); unpack2(kA.y, a2, a3);
        unpack2(kB.x, b0, b1); unpack2(kB.y, b2, b3);
        float dpA = a0 * q0 + a1 * q1 + a2 * q2 + a3 * q3;
        float dpB = b0 * q0 + b1 * q1 + b2 * q2 + b3 * q3;
        dpA += __shfl_xor(dpA, 1, 8); dpB += __shfl_xor(dpB, 1, 8);
        dpA += __shfl_xor(dpA, 2, 8); dpB += __shfl_xor(dpB, 2, 8);
        dpA += __shfl_xor(dpA, 4, 8); dpB += __shfl_xor(dpB, 4, 8);
        float wA = __expf(dpA * rp), wB = __expf(dpB * rp);
        unpack2(vA.x, a0, a1); unpack2(vA.y, a2, a3);
        unpack2(vB.x, b0, b1); unpack2(vB.y, b2, b3);
        denom += wA + wB;
        s0 += wA * a0 + wB * b0; s1 += wA * a1 + wB * b1;
        s2 += wA * a2 + wB * b2; s3 += wA * a3 + wB * b3;
    }
    if (i < end) {
        const unsigned* rA = kv + (size_t)srcs[i] * 128;
        uint2 kA = *(const uint2*)(rA + j * 2);
        uint2 vA = *(const uint2*)(rA + 64 + j * 2);
        float a0, a1, a2, a3;
        unpack2(kA.x, a0, a1); unpack2(kA.y, a2, a3);
        float dp = a0 * q0 + a1 * q1 + a2 * q2 + a3 * q3;
        dp += __shfl_xor(dp, 1, 8);
        dp += __shfl_xor(dp, 2, 8);
        dp += __shfl_xor(dp, 4, 8);
        float w = __expf(dp * rp);
        unpack2(vA.x, a0, a1); unpack2(vA.y, a2, a3);
        denom += w;
        s0 += w * a0; s1 += w * a1; s2 += w * a2; s3 += w * a3;
    }
    float r = 1.0f / (denom + 1e-16f);
    o0 += s0 * r; o1 += s1 * r; o2 += s2 * r; o3 += s3 * r;
}

// ---------- visit-dst edges: relations 0 and 2 merged ----------
__global__ __launch_bounds__(256) void edge_vis(
    const int* __restrict__ rp0, const int* __restrict__ s0, const unsigned* __restrict__ kv0,
    const int* __restrict__ rp2, const int* __restrict__ s2, const unsigned* __restrict__ kv2,
    const unsigned* __restrict__ qv, const float* __restrict__ relPl,
    unsigned* __restrict__ agg, int Nd)
{
    int nid = (int)((blockIdx.x * 256u + threadIdx.x) >> 5);
    int j = threadIdx.x & 31;
    if (nid >= Nd) return;
    int head = j >> 3;
    uint2 q2 = *(const uint2*)(qv + (size_t)nid * 64 + j * 2);
    float q0, q1, qq2, q3;
    unpack2(q2.x, q0, q1); unpack2(q2.y, qq2, q3);
    float rpA = relPl[0 * H + head] * RSC;
    float rpB = relPl[2 * H + head] * RSC;
    float o0 = 0.f, o1 = 0.f, o2 = 0.f, o3 = 0.f;
    rel_accum32(rp0, s0, kv0, nid, j, q0, q1, qq2, q3, rpA, o0, o1, o2, o3);
    rel_accum32(rp2, s2, kv2, nid, j, q0, q1, qq2, q3, rpB, o0, o1, o2, o3);
    uint2 o; o.x = pack2(o0, o1); o.y = pack2(o2, o3);
    *(uint2*)(agg + (size_t)nid * 64 + j * 2) = o;
}

// ---------- code-dst edges: relation 1 (agg may alias qv: own-row read precedes write) ----------
__global__ __launch_bounds__(256) void edge_code(
    const int* __restrict__ rp1, const int* __restrict__ s1, const unsigned* __restrict__ kv1,
    const unsigned* __restrict__ qv, const float* __restrict__ relPh,
    unsigned* __restrict__ agg, int Nd)
{
    int nid = (int)((blockIdx.x * 256u + threadIdx.x) >> 5);
    int j = threadIdx.x & 31;
    if (nid >= Nd) return;
    int head = j >> 3;
    uint2 q2 = *(const uint2*)(qv + (size_t)nid * 64 + j * 2);
    float q0, q1, qq2, q3;
    unpack2(q2.x, q0, q1); unpack2(q2.y, qq2, q3);
    float rp = relPh[head] * RSC;
    float o0 = 0.f, o1 = 0.f, o2 = 0.f, o3 = 0.f;
    rel_accum32(rp1, s1, kv1, nid, j, q0, q1, qq2, q3, rp, o0, o1, o2, o3);
    uint2 o; o.x = pack2(o0, o1); o.y = pack2(o2, o3);
    *(uint2*)(agg + (size_t)nid * 64 + j * 2) = o;
}

// ---------- final: layer-1 visit update fused with patient gather + linear ----------
__global__ void final_fused(const ushort_t* __restrict__ aggV, const ushort_t* __restrict__ xs0,
                            const int* __restrict__ slices,
                            const float* __restrict__ aWp, const float* __restrict__ abp,
                            const float* __restrict__ skipp,
                            const float* __restrict__ Wl, const float* __restrict__ bl,
                            float* __restrict__ out)
{
    __shared__ float ga[C];
    __shared__ float xr[C];
    int b = blockIdx.x, o = threadIdx.x;
    int row = slices[b + 1] - 1;
    ga[o] = gelu_t(bf2f(aggV[(size_t)row * C + o]));
    __syncthreads();
    float y = abp[o];
    #pragma unroll 4
    for (int c = 0; c < C; ++c) y += ga[c] * aWp[c * C + o];
    float g = 1.0f / (1.0f + __expf(-skipp[0]));
    xr[o] = g * y + (1.f - g) * bf2f(xs0[(size_t)row * C + o]);
    __syncthreads();
    float acc = bl[o];
    #pragma unroll 4
    for (int c = 0; c < C; ++c) acc += xr[c] * Wl[c * C + o];
    out[(size_t)b * C + o] = acc;
}

extern "C" void kernel_launch(void* const* d_in, const int* in_sizes, int n_in,
                              void* d_out, int out_size, void* d_ws, size_t ws_size,
                              hipStream_t stream)
{
    (void)n_in;
    const float* x_visit = (const float*)d_in[0];
    const float* x_code  = (const float*)d_in[1];
    const int* slices    = (const int*)d_in[5];
    const float* lin0_W  = (const float*)d_in[6];
    const float* lin0_b  = (const float*)d_in[7];
    const float* kW  = (const float*)d_in[8];
    const float* kb  = (const float*)d_in[9];
    const float* qW  = (const float*)d_in[10];
    const float* qb  = (const float*)d_in[11];
    const float* vW  = (const float*)d_in[12];
    const float* vb  = (const float*)d_in[13];
    const float* aW  = (const float*)d_in[14];
    const float* ab  = (const float*)d_in[15];
    const float* skip = (const float*)d_in[16];
    const float* relA = (const float*)d_in[17];
    const float* relM = (const float*)d_in[18];
    const float* relP = (const float*)d_in[19];
    const float* linW = (const float*)d_in[20];
    const float* linb = (const float*)d_in[21];

    const int NV = in_sizes[0] / C;
    const int NC = in_sizes[1] / C;
    const int NN = NV > NC ? NV : NC;
    const int B = in_sizes[5] - 1;

    const int* eptr[3] = {(const int*)d_in[2], (const int*)d_in[3], (const int*)d_in[4]};
    const int Ecnt[3] = {in_sizes[2] / 2, in_sizes[3] / 2, in_sizes[4] / 2};
    const int Ndrel[3] = {NV, NC, NV};

    // ---- workspace plan with aliased regions; fits measured ~359.37 MB ----
    size_t off = 0;
    auto AL = [&](size_t bytes) { size_t c = off; off += (bytes + 255) & ~(size_t)255; return c; };
    size_t o_xs0  = AL((size_t)NV * C * 2);
    size_t o_xs1  = AL((size_t)NC * C * 2);
    size_t o_q0   = AL((size_t)NV * C * 2);
    size_t o_q1   = AL((size_t)NC * C * 2);   // q1; re-used in-place as aggC after l=0 edge_code
    size_t o_aggV = AL((size_t)NV * C * 2);
    size_t o_rp[3], o_srcs[3];
    for (int e = 0; e < 3; ++e) {
        o_rp[e]   = AL(((size_t)Ndrel[e] + 1) * 4);
        o_srcs[e] = AL((size_t)Ecnt[e] * 4);
    }
    size_t o_wp   = AL(((size_t)NN + 1) * 4);
    size_t o_part = AL(4096);
    size_t o_fw   = AL((size_t)12 * (CC + C) * 4);
    size_t o_wt   = AL((size_t)22 * CC * 2);
    size_t o_RA   = AL((size_t)NC * 2 * C * 2);   // kv0, later kv1
    size_t o_RB   = AL((size_t)NV * 2 * C * 2);   // kv2 only
    size_t total = off;

    if (ws_size < total) {
        float v = 30.0f + (float)((double)ws_size * 1e-9);
        diag_fill<<<(out_size + 255) / 256, 256, 0, stream>>>((float*)d_out, out_size, v);
        return;
    }

    char* base = (char*)d_ws;
    ushort_t* xs0  = (ushort_t*)(base + o_xs0);
    ushort_t* xs1  = (ushort_t*)(base + o_xs1);
    ushort_t* q0   = (ushort_t*)(base + o_q0);
    ushort_t* q1   = (ushort_t*)(base + o_q1);
    ushort_t* aggV = (ushort_t*)(base + o_aggV);
    ushort_t* aggC = q1;   // alias: q1 dead after l=0 edge_code (in-place own-row write)
    int* rp_[3]; int* srcs_[3];
    for (int e = 0; e < 3; ++e) { rp_[e] = (int*)(base + o_rp[e]); srcs_[e] = (int*)(base + o_srcs[e]); }
    int* wp   = (int*)(base + o_wp);
    int* part = (int*)(base + o_part);
    float* fw = (float*)(base + o_fw);
    ushort_t* wt = (ushort_t*)(base + o_wt);
    ushort_t* kv0  = (ushort_t*)(base + o_RA);
    ushort_t* kv1  = (ushort_t*)(base + o_RA);
    ushort_t* kv2  = (ushort_t*)(base + o_RB);

    auto wt_q = [&](int l, int t) { return wt + (size_t)(2 + l * 2 + t) * CC; };
    auto wt_a = [&](int l, int t) { return wt + (size_t)(6 + l * 2 + t) * CC; };
    auto wt_f = [&](int le, int which) { return wt + (size_t)(10 + le * 2 + which) * CC; };
    auto fb   = [&](int le, int which) { return fw + (size_t)(le * 2 + which) * (CC + C) + CC; };

    // 1) weight prep
    fuse_weights<<<12, 256, 0, stream>>>(kW, kb, vW, vb, relA, relM, fw);
    trans_w<<<22, 256, 0, stream>>>(lin0_W, qW, aW, fw, wt);

    // 2) CSR build per relation
    for (int e = 0; e < 3; ++e) {
        int Nd = Ndrel[e], E = Ecnt[e];
        int nb = (Nd + SC - 1) / SC;
        hipMemsetAsync(wp, 0, (size_t)Nd * 4, stream);
        hist_k<<<(E + 255) / 256, 256, 0, stream>>>(eptr[e], E, wp);
        scan1<<<nb, 256, 0, stream>>>(wp, Nd, part);
        scan2<<<1, 64, 0, stream>>>(part, nb);
        scan3<<<nb, 256, 0, stream>>>(wp, Nd, part, rp_[e]);
        hipMemcpyAsync(wp, rp_[e], (size_t)Nd * 4, hipMemcpyDeviceToDevice, stream);
        scatter_k<<<(E + 255) / 256, 256, 0, stream>>>(eptr[e], E, wp, srcs_[e]);
    }

    const int tilesV = (NV + 63) / 64, tilesC = (NC + 63) / 64;
    unsigned gV = (unsigned)(((size_t)NV * 32 + 255) / 256);
    unsigned gC = (unsigned)(((size_t)NC * 32 + 255) / 256);

    // ---- layer 0: combined input-proj + projections (no aliasing) ----
    {
        FusedArgs aC = {}, aV = {};
        aC.X = x_code; aC.W1 = wt + CC; aC.b1 = lin0_b + C; aC.Y1 = xs1;
        aC.N = NC; aC.nw = 3;
        aC.j[0] = {wt_q(0, 1), qb + 1 * C, q1, C};
        aC.j[1] = {wt_f(0, 0), fb(0, 0), kv0, 2 * C};
        aC.j[2] = {wt_f(0, 1), fb(0, 1), kv0 + C, 2 * C};
        aV.X = x_visit; aV.W1 = wt; aV.b1 = lin0_b; aV.Y1 = xs0;
        aV.N = NV; aV.nw = 3;
        aV.j[0] = {wt_q(0, 0), qb + 0 * C, q0, C};
        aV.j[1] = {wt_f(2, 0), fb(2, 0), kv2, 2 * C};
        aV.j[2] = {wt_f(2, 1), fb(2, 1), kv2 + C, 2 * C};
        fusedProj<0, 0, 1><<<(unsigned)(tilesC + tilesV), 256, 0, stream>>>(aC, aV, tilesC);
    }
    edge_vis<<<gV, 256, 0, stream>>>(
        rp_[0], srcs_[0], (const unsigned*)kv0,
        rp_[2], srcs_[2], (const unsigned*)kv2,
        (const unsigned*)q0, relP + 0 * 3 * H, (unsigned*)aggV, NV);
    proj2<<<(unsigned)tilesV, 256, 0, stream>>>(
        xs0, wt_f(1, 0), fb(1, 0), wt_f(1, 1), fb(1, 1), kv1, kv1 + C, NV);
    // aggC written in-place over q1 (own-row read precedes write)
    edge_code<<<gC, 256, 0, stream>>>(
        rp_[1], srcs_[1], (const unsigned*)kv1,
        (const unsigned*)q1, relP + (size_t)1 * H, (unsigned*)aggC, NC);

    // ---- layer 1: combined update+projection launch (aggC in q1-space, no R_B conflict) ----
    {
        FusedArgs aC = {}, aV = {};
        // code side: update (xs1 store DEAD -> Y1=null) + chained kv0
        aC.X = aggC; aC.W1 = wt_a(0, 1); aC.b1 = ab + 1 * C; aC.Y1 = nullptr;
        aC.Old = xs1; aC.skipp = skip + 1; aC.N = NC; aC.nw = 2;
        aC.j[0] = {wt_f(3, 0), fb(3, 0), kv0, 2 * C};
        aC.j[1] = {wt_f(3, 1), fb(3, 1), kv0 + C, 2 * C};
        aC.j[2] = {nullptr, nullptr, nullptr, 0};
        // visit side: update + chained {q0, kv2}
        aV.X = aggV; aV.W1 = wt_a(0, 0); aV.b1 = ab + 0 * C; aV.Y1 = xs0;
        aV.Old = xs0; aV.skipp = skip + 0; aV.N = NV; aV.nw = 3;
        aV.j[0] = {wt_q(1, 0), qb + 2 * C, q0, C};
        aV.j[1] = {wt_f(5, 0), fb(5, 0), kv2, 2 * C};
        aV.j[2] = {wt_f(5, 1), fb(5, 1), kv2 + C, 2 * C};
        fusedProj<1, 1, 2><<<(unsigned)(tilesC + tilesV), 256, 0, stream>>>(aC, aV, tilesC);
    }
    edge_vis<<<gV, 256, 0, stream>>>(
        rp_[0], srcs_[0], (const unsigned*)kv0,
        rp_[2], srcs_[2], (const unsigned*)kv2,
        (const unsigned*)q0, relP + (size_t)3 * H, (unsigned*)aggV, NV);

    // final: layer-1 visit update + patient gather + linear (only 1024 rows needed)
    final_fused<<<B, 128, 0, stream>>>(
        aggV, xs0, slices, aW + (size_t)2 * CC, ab + 2 * C, skip + 2,
        linW, linb, (float*)d_out);
}